// Round 3
// baseline (1046.610 us; speedup 1.0000x reference)
//
#include <hip/hip_runtime.h>

#define S_LEN 2048
#define I_IN  32
#define H_DIM 64
#define O_DIM 32
#define NSEQ  256
#define NROWS (NSEQ * S_LEN)          // 524288
#define OBS_ELEMS (NROWS * O_DIM)     // 16777216
#define HID_ELEMS (NROWS * H_DIM)     // 33554432

// ---------------------------------------------------------------------------
// Kernel 1: pre[row][g] = bih[g]+bhh[g] + sum_i x[row][i]*Wih[g][i]
// (unchanged from R2)
// ---------------------------------------------------------------------------
__global__ __launch_bounds__(256) void pre_kernel(
    const float* __restrict__ x,
    const float* __restrict__ Wih,
    const float* __restrict__ bih,
    const float* __restrict__ bhh,
    float* __restrict__ pre)
{
    __shared__ float ws[I_IN][68];
    __shared__ float bsh[H_DIM];

    const int tid = threadIdx.x;
#pragma unroll
    for (int s = 0; s < 8; ++s) {
        const int e = tid + 256 * s;          // e = g*32 + i
        ws[e & 31][e >> 5] = Wih[e];
    }
    if (tid < H_DIM) bsh[tid] = bih[tid] + bhh[tid];
    __syncthreads();

    const int r    = tid & 127;
    const int half = tid >> 7;                // wave-uniform
    const size_t row = (size_t)blockIdx.x * 128 + r;
    const int o0 = half * 32;

    float4 xr[8];
    const float4* xg = (const float4*)(x + row * I_IN);
#pragma unroll
    for (int k = 0; k < 8; ++k) xr[k] = xg[k];

    float4 acc[8];
#pragma unroll
    for (int j = 0; j < 8; ++j) acc[j] = *(const float4*)&bsh[o0 + 4 * j];

#pragma unroll
    for (int k = 0; k < 8; ++k) {
        const float xi0 = xr[k].x, xi1 = xr[k].y, xi2 = xr[k].z, xi3 = xr[k].w;
#pragma unroll
        for (int j = 0; j < 8; ++j) {
            const float4 w0 = *(const float4*)&ws[4 * k + 0][o0 + 4 * j];
            const float4 w1 = *(const float4*)&ws[4 * k + 1][o0 + 4 * j];
            const float4 w2 = *(const float4*)&ws[4 * k + 2][o0 + 4 * j];
            const float4 w3 = *(const float4*)&ws[4 * k + 3][o0 + 4 * j];
            acc[j].x = fmaf(xi0, w0.x, acc[j].x);
            acc[j].y = fmaf(xi0, w0.y, acc[j].y);
            acc[j].z = fmaf(xi0, w0.z, acc[j].z);
            acc[j].w = fmaf(xi0, w0.w, acc[j].w);
            acc[j].x = fmaf(xi1, w1.x, acc[j].x);
            acc[j].y = fmaf(xi1, w1.y, acc[j].y);
            acc[j].z = fmaf(xi1, w1.z, acc[j].z);
            acc[j].w = fmaf(xi1, w1.w, acc[j].w);
            acc[j].x = fmaf(xi2, w2.x, acc[j].x);
            acc[j].y = fmaf(xi2, w2.y, acc[j].y);
            acc[j].z = fmaf(xi2, w2.z, acc[j].z);
            acc[j].w = fmaf(xi2, w2.w, acc[j].w);
            acc[j].x = fmaf(xi3, w3.x, acc[j].x);
            acc[j].y = fmaf(xi3, w3.y, acc[j].y);
            acc[j].z = fmaf(xi3, w3.z, acc[j].z);
            acc[j].w = fmaf(xi3, w3.w, acc[j].w);
        }
    }

    float4* pr = (float4*)(pre + row * H_DIM + o0);
#pragma unroll
    for (int j = 0; j < 8; ++j) pr[j] = acc[j];
}

// ---------------------------------------------------------------------------
// Kernel 2: serial scan. One wave per sequence; lane g owns h[g].
// R2 was issue-bound: 64 readlane + 64 fma on the chain (567 cy/step).
// Now: h broadcast mostly via WAVE-UNIFORM ds_read_b128 (1 instr = 4 h values
// to all lanes) from a double-buffered 64-float LDS slot; h=0..15 stay on
// readlane so their FMAs execute while the LDS write->read turnaround is in
// flight. Single wave -> NO barriers (compiler orders ds ops via lgkmcnt;
// per-wave LDS is in-order). ~120 instrs/step vs ~220.
// ---------------------------------------------------------------------------
__device__ __forceinline__ float rl(float v, int l)
{
    return __int_as_float(__builtin_amdgcn_readlane(__float_as_int(v), l));
}

__global__ __launch_bounds__(64, 1) void rnn_scan_kernel(
    const float* __restrict__ Whh,
    float* __restrict__ hidden,   // contains pre on entry; h written in place
    float* __restrict__ hlast)
{
    const int q = blockIdx.x;
    const int g = threadIdx.x;

    __shared__ float hsA[H_DIM];
    __shared__ float hsB[H_DIM];

    float whh[H_DIM];
#pragma unroll
    for (int h = 0; h < H_DIM; ++h) whh[h] = Whh[g * H_DIM + h];

    float* hq = hidden + (size_t)q * S_LEN * H_DIM;

    float hv = 0.0f;          // lane g's h(t-1)[g]
    hsA[g] = 0.0f;            // h(-1) = 0 lives in A (single wave: no barrier)

    float buf[8];
#pragma unroll
    for (int j = 0; j < 8; ++j) buf[j] = hq[j * H_DIM + g];

    // one step: read h(t-1) from rs, write h(t) to ws
    auto step = [&](const float (&rs)[H_DIM], float (&ws)[H_DIM],
                    const float pv, const int t) {
        // h = 0..15 via readlane: ready immediately, covers LDS turnaround
        float a0 = pv, a1 = 0.0f;
#pragma unroll
        for (int hh = 0; hh < 16; hh += 2) {
            a0 = fmaf(whh[hh + 0], rl(hv, hh + 0), a0);
            a1 = fmaf(whh[hh + 1], rl(hv, hh + 1), a1);
        }
        // h = 16..63 via uniform-address LDS broadcast reads
        float a2 = 0.0f, a3 = 0.0f;
#pragma unroll
        for (int k = 0; k < 12; ++k) {
            const float4 hb = *(const float4*)&rs[16 + 4 * k];
            a0 = fmaf(whh[16 + 4 * k + 0], hb.x, a0);
            a1 = fmaf(whh[16 + 4 * k + 1], hb.y, a1);
            a2 = fmaf(whh[16 + 4 * k + 2], hb.z, a2);
            a3 = fmaf(whh[16 + 4 * k + 3], hb.w, a3);
        }
        const float z = (a0 + a1) + (a2 + a3);
        // tanh(z) = 1 - 2/(exp(2z)+1): branchless, NaN-free for finite z
        const float e = __expf(2.0f * z);
        hv = fmaf(-2.0f, __builtin_amdgcn_rcpf(e + 1.0f), 1.0f);

        ws[g] = hv;               // ds_write for next step's broadcasts
        hq[t * H_DIM + g] = hv;   // trailing store, never waited on
    };

    for (int tb = 0; tb < S_LEN - 8; tb += 8) {
        float nbuf[8];
        // prefetch next macro-block's pre: 8 steps (>1500cy) of cover
#pragma unroll
        for (int j = 0; j < 8; ++j) nbuf[j] = hq[(tb + 8 + j) * H_DIM + g];
        // 8 steps, A/B alternation static (t parity == j parity)
        step(hsA, hsB, buf[0], tb + 0);
        step(hsB, hsA, buf[1], tb + 1);
        step(hsA, hsB, buf[2], tb + 2);
        step(hsB, hsA, buf[3], tb + 3);
        step(hsA, hsB, buf[4], tb + 4);
        step(hsB, hsA, buf[5], tb + 5);
        step(hsA, hsB, buf[6], tb + 6);
        step(hsB, hsA, buf[7], tb + 7);
#pragma unroll
        for (int j = 0; j < 8; ++j) buf[j] = nbuf[j];
    }
    {
        const int tb = S_LEN - 8;   // tail macro-block, no prefetch
        step(hsA, hsB, buf[0], tb + 0);
        step(hsB, hsA, buf[1], tb + 1);
        step(hsA, hsB, buf[2], tb + 2);
        step(hsB, hsA, buf[3], tb + 3);
        step(hsA, hsB, buf[4], tb + 4);
        step(hsB, hsA, buf[5], tb + 5);
        step(hsA, hsB, buf[6], tb + 6);
        step(hsB, hsA, buf[7], tb + 7);
    }

    hlast[q * H_DIM + g] = hv;
}

// ---------------------------------------------------------------------------
// Kernel 3: obs[row][o] = sum_h hidden[row][h]*W_fc[o][h] + b_fc[o]
// (unchanged from R2)
// ---------------------------------------------------------------------------
__global__ __launch_bounds__(256) void obs_kernel(
    const float* __restrict__ hidden,
    const float* __restrict__ Wfc,
    const float* __restrict__ bfc,
    float* __restrict__ obs)
{
    __shared__ float wt[H_DIM][36];
    __shared__ float bsh[O_DIM];

    const int tid = threadIdx.x;
#pragma unroll
    for (int s = 0; s < 8; ++s) {
        const int e = tid + 256 * s;          // e = o*64 + h
        wt[e & 63][e >> 6] = Wfc[e];
    }
    if (tid < O_DIM) bsh[tid] = bfc[tid];
    __syncthreads();

    const int r    = tid & 127;
    const int half = tid >> 7;                // wave-uniform
    const size_t row = (size_t)blockIdx.x * 128 + r;
    const int o0 = half * 16;

    float4 hr[16];
    const float4* hg = (const float4*)(hidden + row * H_DIM);
#pragma unroll
    for (int k = 0; k < 16; ++k) hr[k] = hg[k];

    float4 acc[4];
#pragma unroll
    for (int j = 0; j < 4; ++j) acc[j] = *(const float4*)&bsh[o0 + 4 * j];

#pragma unroll
    for (int k = 0; k < 16; ++k) {
        const float h0 = hr[k].x, h1 = hr[k].y, h2 = hr[k].z, h3 = hr[k].w;
#pragma unroll
        for (int j = 0; j < 4; ++j) {
            const float4 w0 = *(const float4*)&wt[4 * k + 0][o0 + 4 * j];
            const float4 w1 = *(const float4*)&wt[4 * k + 1][o0 + 4 * j];
            const float4 w2 = *(const float4*)&wt[4 * k + 2][o0 + 4 * j];
            const float4 w3 = *(const float4*)&wt[4 * k + 3][o0 + 4 * j];
            acc[j].x = fmaf(h0, w0.x, acc[j].x);
            acc[j].y = fmaf(h0, w0.y, acc[j].y);
            acc[j].z = fmaf(h0, w0.z, acc[j].z);
            acc[j].w = fmaf(h0, w0.w, acc[j].w);
            acc[j].x = fmaf(h1, w1.x, acc[j].x);
            acc[j].y = fmaf(h1, w1.y, acc[j].y);
            acc[j].z = fmaf(h1, w1.z, acc[j].z);
            acc[j].w = fmaf(h1, w1.w, acc[j].w);
            acc[j].x = fmaf(h2, w2.x, acc[j].x);
            acc[j].y = fmaf(h2, w2.y, acc[j].y);
            acc[j].z = fmaf(h2, w2.z, acc[j].z);
            acc[j].w = fmaf(h2, w2.w, acc[j].w);
            acc[j].x = fmaf(h3, w3.x, acc[j].x);
            acc[j].y = fmaf(h3, w3.y, acc[j].y);
            acc[j].z = fmaf(h3, w3.z, acc[j].z);
            acc[j].w = fmaf(h3, w3.w, acc[j].w);
        }
    }

    float4* op = (float4*)(obs + row * O_DIM + o0);
#pragma unroll
    for (int j = 0; j < 4; ++j) op[j] = acc[j];
}

extern "C" void kernel_launch(void* const* d_in, const int* in_sizes, int n_in,
                              void* d_out, int out_size, void* d_ws, size_t ws_size,
                              hipStream_t stream)
{
    const float* x   = (const float*)d_in[0];
    const float* Wih = (const float*)d_in[1];
    const float* bih = (const float*)d_in[2];
    const float* Whh = (const float*)d_in[3];
    const float* bhh = (const float*)d_in[4];
    const float* Wfc = (const float*)d_in[5];
    const float* bfc = (const float*)d_in[6];

    float* out    = (float*)d_out;
    float* obs    = out;                         // [8,32,2048,32]
    float* hidden = out + (size_t)OBS_ELEMS;     // [8,32,2048,64]
    float* hlast  = hidden + (size_t)HID_ELEMS;  // [8,32,64]

    // pre is materialized IN the hidden buffer (same shape), then the scan
    // overwrites it in place (reads run 8 steps ahead of writes).
    pre_kernel<<<NROWS / 128, 256, 0, stream>>>(x, Wih, bih, bhh, hidden);
    rnn_scan_kernel<<<NSEQ, 64, 0, stream>>>(Whh, hidden, hlast);
    obs_kernel<<<NROWS / 128, 256, 0, stream>>>(hidden, Wfc, bfc, obs);
}

// Round 5
// 797.843 us; speedup vs baseline: 1.3118x; 1.3118x over previous
//
#include <hip/hip_runtime.h>

#define S_LEN 2048
#define I_IN  32
#define H_DIM 64
#define O_DIM 32
#define NSEQ  256
#define NROWS (NSEQ * S_LEN)          // 524288
#define OBS_ELEMS (NROWS * O_DIM)     // 16777216
#define HID_ELEMS (NROWS * H_DIM)     // 33554432

// ---------------------------------------------------------------------------
// Kernel 1: pre[row][g] = bih[g]+bhh[g] + sum_i x[row][i]*Wih[g][i]
// Coalesced: x tile (128 rows x 32) staged into LDS with linear float4
// copies; lane g owns output column g, so x-row reads are wave-uniform LDS
// broadcasts and the pre store is 64 contiguous dwords (256B, coalesced).
// ---------------------------------------------------------------------------
__global__ __launch_bounds__(256) void pre_kernel(
    const float* __restrict__ x,
    const float* __restrict__ Wih,
    const float* __restrict__ bih,
    const float* __restrict__ bhh,
    float* __restrict__ pre)
{
    __shared__ float4 xs4[1024];   // 128 rows x 32 floats = 16 KB

    const int tid = threadIdx.x;
    const size_t row0 = (size_t)blockIdx.x * 128;

    // linear coalesced stage: 1024 float4
    const float4* xg = (const float4*)(x + row0 * I_IN);
#pragma unroll
    for (int s = 0; s < 4; ++s) xs4[tid + 256 * s] = xg[tid + 256 * s];

    const int g = tid & 63;
    // lane-owned W_ih row (8 KB total, L2-hot across blocks)
    float wih[I_IN];
    const float4* wg = (const float4*)(Wih + g * I_IN);
#pragma unroll
    for (int k = 0; k < 8; ++k) {
        const float4 wv = wg[k];
        wih[4 * k + 0] = wv.x; wih[4 * k + 1] = wv.y;
        wih[4 * k + 2] = wv.z; wih[4 * k + 3] = wv.w;
    }
    const float bias = bih[g] + bhh[g];

    __syncthreads();

    const int w = tid >> 6;            // wave id 0..3; rows w*32 .. w*32+31
#pragma unroll 2
    for (int j = 0; j < 32; ++j) {
        const int r = w * 32 + j;                       // wave-uniform
        const float4* xr = &xs4[r * 8];                 // uniform addr -> broadcast
        float a0 = bias, a1 = 0.0f, a2 = 0.0f, a3 = 0.0f;
#pragma unroll
        for (int k = 0; k < 8; ++k) {
            const float4 xb = xr[k];
            a0 = fmaf(wih[4 * k + 0], xb.x, a0);
            a1 = fmaf(wih[4 * k + 1], xb.y, a1);
            a2 = fmaf(wih[4 * k + 2], xb.z, a2);
            a3 = fmaf(wih[4 * k + 3], xb.w, a3);
        }
        pre[(row0 + r) * H_DIM + g] = (a0 + a1) + (a2 + a3);   // 256B coalesced
    }
}

// ---------------------------------------------------------------------------
// Kernel 2: serial scan — EXACT R2 version (known-good, 484 us).
// One wave per sequence; lane g owns h[g]; h broadcast via readlane
// intrinsics (compiler handles all hazard fencing). No LDS, no barriers.
// R4's hand-asm variant (physical s88-s95 + pinned schedule) failed
// correctness; reverted to isolate it. 8-deep pre prefetch stays.
// ---------------------------------------------------------------------------
__device__ __forceinline__ float rl(float v, int l)
{
    return __int_as_float(__builtin_amdgcn_readlane(__float_as_int(v), l));
}

__device__ __forceinline__ float rnn_step(float pv, float hv, const float* whh)
{
    float z0 = pv, z1 = 0.0f, z2 = 0.0f, z3 = 0.0f;
    float z4 = 0.0f, z5 = 0.0f, z6 = 0.0f, z7 = 0.0f;
#pragma unroll
    for (int h = 0; h < H_DIM; h += 8) {
        z0 = fmaf(whh[h + 0], rl(hv, h + 0), z0);
        z1 = fmaf(whh[h + 1], rl(hv, h + 1), z1);
        z2 = fmaf(whh[h + 2], rl(hv, h + 2), z2);
        z3 = fmaf(whh[h + 3], rl(hv, h + 3), z3);
        z4 = fmaf(whh[h + 4], rl(hv, h + 4), z4);
        z5 = fmaf(whh[h + 5], rl(hv, h + 5), z5);
        z6 = fmaf(whh[h + 6], rl(hv, h + 6), z6);
        z7 = fmaf(whh[h + 7], rl(hv, h + 7), z7);
    }
    const float z = ((z0 + z1) + (z2 + z3)) + ((z4 + z5) + (z6 + z7));
    // tanh(z) = 1 - 2/(exp(2z)+1): branchless, NaN-free for finite z
    const float e = __expf(2.0f * z);
    return fmaf(-2.0f, __builtin_amdgcn_rcpf(e + 1.0f), 1.0f);
}

__global__ __launch_bounds__(64, 1) void rnn_scan_kernel(
    const float* __restrict__ Whh,
    float* __restrict__ hidden,   // contains pre on entry; h written in place
    float* __restrict__ hlast)
{
    const int q = blockIdx.x;
    const int g = threadIdx.x;

    float whh[H_DIM];
#pragma unroll
    for (int h = 0; h < H_DIM; ++h) whh[h] = Whh[g * H_DIM + h];

    float* hq = hidden + (size_t)q * S_LEN * H_DIM;

    float hv = 0.0f;
    float buf[8];
#pragma unroll
    for (int j = 0; j < 8; ++j) buf[j] = hq[j * H_DIM + g];

    for (int tb = 0; tb < S_LEN - 8; tb += 8) {
        float nbuf[8];
        // issue next macro-block's loads first: ~8 steps (>1500cy) of cover
#pragma unroll
        for (int j = 0; j < 8; ++j) nbuf[j] = hq[(tb + 8 + j) * H_DIM + g];
#pragma unroll
        for (int j = 0; j < 8; ++j) {
            hv = rnn_step(buf[j], hv, whh);
            hq[(tb + j) * H_DIM + g] = hv;
        }
#pragma unroll
        for (int j = 0; j < 8; ++j) buf[j] = nbuf[j];
    }
    // tail macro-block: no prefetch
#pragma unroll
    for (int j = 0; j < 8; ++j) {
        hv = rnn_step(buf[j], hv, whh);
        hq[(S_LEN - 8 + j) * H_DIM + g] = hv;
    }

    hlast[q * H_DIM + g] = hv;
}

// ---------------------------------------------------------------------------
// Kernel 3: obs[row][o] = sum_h hidden[row][h]*W_fc[o][h] + b_fc[o]
// Coalesced: hidden tile (128 rows x 64) staged linearly into LDS; lane
// o = tid&31 owns output column o, half-waves split adjacent rows. Obs
// store is lane-contiguous.
// ---------------------------------------------------------------------------
__global__ __launch_bounds__(256) void obs_kernel(
    const float* __restrict__ hidden,
    const float* __restrict__ Wfc,
    const float* __restrict__ bfc,
    float* __restrict__ obs)
{
    __shared__ float4 hs4[2048];   // 128 rows x 64 floats = 32 KB

    const int tid = threadIdx.x;
    const size_t row0 = (size_t)blockIdx.x * 128;

    const float4* hg = (const float4*)(hidden + row0 * H_DIM);
#pragma unroll
    for (int s = 0; s < 8; ++s) hs4[tid + 256 * s] = hg[tid + 256 * s];

    const int o  = tid & 31;
    const int hi = (tid >> 5) & 1;   // half-wave -> row parity
    float wfc[H_DIM];
    const float4* wg = (const float4*)(Wfc + o * H_DIM);
#pragma unroll
    for (int k = 0; k < 16; ++k) {
        const float4 wv = wg[k];
        wfc[4 * k + 0] = wv.x; wfc[4 * k + 1] = wv.y;
        wfc[4 * k + 2] = wv.z; wfc[4 * k + 3] = wv.w;
    }
    const float bias = bfc[o];

    __syncthreads();

    const int w = tid >> 6;           // wave id; rows w*32 .. w*32+31
#pragma unroll 2
    for (int j = 0; j < 16; ++j) {
        const int r = w * 32 + 2 * j + hi;              // 2 rows per iter
        const float4* hr = &hs4[r * 16];                // 2 unique addrs/instr
        float a0 = bias, a1 = 0.0f, a2 = 0.0f, a3 = 0.0f;
#pragma unroll
        for (int k = 0; k < 16; ++k) {
            const float4 hb = hr[k];
            a0 = fmaf(wfc[4 * k + 0], hb.x, a0);
            a1 = fmaf(wfc[4 * k + 1], hb.y, a1);
            a2 = fmaf(wfc[4 * k + 2], hb.z, a2);
            a3 = fmaf(wfc[4 * k + 3], hb.w, a3);
        }
        obs[(row0 + r) * O_DIM + o] = (a0 + a1) + (a2 + a3);  // coalesced
    }
}

extern "C" void kernel_launch(void* const* d_in, const int* in_sizes, int n_in,
                              void* d_out, int out_size, void* d_ws, size_t ws_size,
                              hipStream_t stream)
{
    const float* x   = (const float*)d_in[0];
    const float* Wih = (const float*)d_in[1];
    const float* bih = (const float*)d_in[2];
    const float* Whh = (const float*)d_in[3];
    const float* bhh = (const float*)d_in[4];
    const float* Wfc = (const float*)d_in[5];
    const float* bfc = (const float*)d_in[6];

    float* out    = (float*)d_out;
    float* obs    = out;                         // [8,32,2048,32]
    float* hidden = out + (size_t)OBS_ELEMS;     // [8,32,2048,64]
    float* hlast  = hidden + (size_t)HID_ELEMS;  // [8,32,64]

    // pre is materialized IN the hidden buffer (same shape), then the scan
    // overwrites it in place (reads run 8 steps ahead of writes).
    pre_kernel<<<NROWS / 128, 256, 0, stream>>>(x, Wih, bih, bhh, hidden);
    rnn_scan_kernel<<<NSEQ, 64, 0, stream>>>(Whh, hidden, hlast);
    obs_kernel<<<NROWS / 128, 256, 0, stream>>>(hidden, Wfc, bfc, obs);
}

// Round 6
// 795.261 us; speedup vs baseline: 1.3161x; 1.0032x over previous
//
#include <hip/hip_runtime.h>

#define S_LEN 2048
#define I_IN  32
#define H_DIM 64
#define O_DIM 32
#define NSEQ  256
#define NROWS (NSEQ * S_LEN)          // 524288
#define OBS_ELEMS (NROWS * O_DIM)     // 16777216
#define HID_ELEMS (NROWS * H_DIM)     // 33554432

// ---------------------------------------------------------------------------
// Kernel 1: pre[row][g] = bih[g]+bhh[g] + sum_i x[row][i]*Wih[g][i]
// (unchanged from R5 — passing)
// ---------------------------------------------------------------------------
__global__ __launch_bounds__(256) void pre_kernel(
    const float* __restrict__ x,
    const float* __restrict__ Wih,
    const float* __restrict__ bih,
    const float* __restrict__ bhh,
    float* __restrict__ pre)
{
    __shared__ float4 xs4[1024];   // 128 rows x 32 floats = 16 KB

    const int tid = threadIdx.x;
    const size_t row0 = (size_t)blockIdx.x * 128;

    const float4* xg = (const float4*)(x + row0 * I_IN);
#pragma unroll
    for (int s = 0; s < 4; ++s) xs4[tid + 256 * s] = xg[tid + 256 * s];

    const int g = tid & 63;
    float wih[I_IN];
    const float4* wg = (const float4*)(Wih + g * I_IN);
#pragma unroll
    for (int k = 0; k < 8; ++k) {
        const float4 wv = wg[k];
        wih[4 * k + 0] = wv.x; wih[4 * k + 1] = wv.y;
        wih[4 * k + 2] = wv.z; wih[4 * k + 3] = wv.w;
    }
    const float bias = bih[g] + bhh[g];

    __syncthreads();

    const int w = tid >> 6;            // wave id 0..3; rows w*32 .. w*32+31
#pragma unroll 2
    for (int j = 0; j < 32; ++j) {
        const int r = w * 32 + j;                       // wave-uniform
        const float4* xr = &xs4[r * 8];                 // uniform addr -> broadcast
        float a0 = bias, a1 = 0.0f, a2 = 0.0f, a3 = 0.0f;
#pragma unroll
        for (int k = 0; k < 8; ++k) {
            const float4 xb = xr[k];
            a0 = fmaf(wih[4 * k + 0], xb.x, a0);
            a1 = fmaf(wih[4 * k + 1], xb.y, a1);
            a2 = fmaf(wih[4 * k + 2], xb.z, a2);
            a3 = fmaf(wih[4 * k + 3], xb.w, a3);
        }
        pre[(row0 + r) * H_DIM + g] = (a0 + a1) + (a2 + a3);   // 256B coalesced
    }
}

// ---------------------------------------------------------------------------
// Kernel 2: serial scan. One wave per sequence; lane g owns h[g].
// R5 baseline (readlane broadcast) = 567 cy/step; VALUBusy says ~440cy of
// VALU issue vs ~280 nominal -> the readlane->SGPR->fma path is the cost
// (4cy readlane issue and/or VALU-SGPR wait states). NOW: broadcast via
// ds_bpermute_b32 with wave-uniform byte index 4k = LDS *crossbar*
// (no LDS memory, no allocation, no barrier, no SGPR writes). All 64
// bpermutes depend only on hv -> fully pipelined; 8-group software
// pipeline (load G+1 || FMA G), all statically indexed. Accumulation tree
// bit-identical to R5 (z_c, c=h mod 8, h ascending).
// ---------------------------------------------------------------------------
__device__ __forceinline__ float bp(int byteidx, int hvi)
{
    return __int_as_float(__builtin_amdgcn_ds_bpermute(byteidx, hvi));
}

#define LOADG(buf, G) \
    buf[0] = bp(4 * (8 * G + 0), hvi); \
    buf[1] = bp(4 * (8 * G + 1), hvi); \
    buf[2] = bp(4 * (8 * G + 2), hvi); \
    buf[3] = bp(4 * (8 * G + 3), hvi); \
    buf[4] = bp(4 * (8 * G + 4), hvi); \
    buf[5] = bp(4 * (8 * G + 5), hvi); \
    buf[6] = bp(4 * (8 * G + 6), hvi); \
    buf[7] = bp(4 * (8 * G + 7), hvi);

#define FMAG(buf, G) \
    z0 = fmaf(whh[8 * G + 0], buf[0], z0); \
    z1 = fmaf(whh[8 * G + 1], buf[1], z1); \
    z2 = fmaf(whh[8 * G + 2], buf[2], z2); \
    z3 = fmaf(whh[8 * G + 3], buf[3], z3); \
    z4 = fmaf(whh[8 * G + 4], buf[4], z4); \
    z5 = fmaf(whh[8 * G + 5], buf[5], z5); \
    z6 = fmaf(whh[8 * G + 6], buf[6], z6); \
    z7 = fmaf(whh[8 * G + 7], buf[7], z7);

__global__ __launch_bounds__(64, 1) void rnn_scan_kernel(
    const float* __restrict__ Whh,
    float* __restrict__ hidden,   // contains pre on entry; h written in place
    float* __restrict__ hlast)
{
    const int q = blockIdx.x;
    const int g = threadIdx.x;

    float whh[H_DIM];
#pragma unroll
    for (int h = 0; h < H_DIM; ++h) whh[h] = Whh[g * H_DIM + h];

    float* hq = hidden + (size_t)q * S_LEN * H_DIM;

    float hv = 0.0f;
    float buf[8];
#pragma unroll
    for (int j = 0; j < 8; ++j) buf[j] = hq[j * H_DIM + g];

    auto step = [&](const float pv, const int t) {
        const int hvi = __float_as_int(hv);
        float z0 = pv, z1 = 0.0f, z2 = 0.0f, z3 = 0.0f;
        float z4 = 0.0f, z5 = 0.0f, z6 = 0.0f, z7 = 0.0f;
        float ba[8], bb[8];
        LOADG(ba, 0)
        LOADG(bb, 1) FMAG(ba, 0)
        LOADG(ba, 2) FMAG(bb, 1)
        LOADG(bb, 3) FMAG(ba, 2)
        LOADG(ba, 4) FMAG(bb, 3)
        LOADG(bb, 5) FMAG(ba, 4)
        LOADG(ba, 6) FMAG(bb, 5)
        LOADG(bb, 7) FMAG(ba, 6)
        FMAG(bb, 7)
        const float z = ((z0 + z1) + (z2 + z3)) + ((z4 + z5) + (z6 + z7));
        // tanh(z) = 1 - 2/(exp(2z)+1): branchless, NaN-free for finite z
        const float e = __expf(2.0f * z);
        hv = fmaf(-2.0f, __builtin_amdgcn_rcpf(e + 1.0f), 1.0f);
        hq[t * H_DIM + g] = hv;   // trailing store, never waited on
    };

    for (int tb = 0; tb < S_LEN - 8; tb += 8) {
        float nbuf[8];
        // prefetch next macro-block's pre: ~8 steps of latency cover
#pragma unroll
        for (int j = 0; j < 8; ++j) nbuf[j] = hq[(tb + 8 + j) * H_DIM + g];
#pragma unroll
        for (int j = 0; j < 8; ++j) step(buf[j], tb + j);
#pragma unroll
        for (int j = 0; j < 8; ++j) buf[j] = nbuf[j];
    }
#pragma unroll
    for (int j = 0; j < 8; ++j) step(buf[j], S_LEN - 8 + j);   // tail

    hlast[q * H_DIM + g] = hv;
}

// ---------------------------------------------------------------------------
// Kernel 3: obs[row][o] = sum_h hidden[row][h]*W_fc[o][h] + b_fc[o]
// (unchanged from R5 — passing)
// ---------------------------------------------------------------------------
__global__ __launch_bounds__(256) void obs_kernel(
    const float* __restrict__ hidden,
    const float* __restrict__ Wfc,
    const float* __restrict__ bfc,
    float* __restrict__ obs)
{
    __shared__ float4 hs4[2048];   // 128 rows x 64 floats = 32 KB

    const int tid = threadIdx.x;
    const size_t row0 = (size_t)blockIdx.x * 128;

    const float4* hg = (const float4*)(hidden + row0 * H_DIM);
#pragma unroll
    for (int s = 0; s < 8; ++s) hs4[tid + 256 * s] = hg[tid + 256 * s];

    const int o  = tid & 31;
    const int hi = (tid >> 5) & 1;   // half-wave -> row parity
    float wfc[H_DIM];
    const float4* wg = (const float4*)(Wfc + o * H_DIM);
#pragma unroll
    for (int k = 0; k < 16; ++k) {
        const float4 wv = wg[k];
        wfc[4 * k + 0] = wv.x; wfc[4 * k + 1] = wv.y;
        wfc[4 * k + 2] = wv.z; wfc[4 * k + 3] = wv.w;
    }
    const float bias = bfc[o];

    __syncthreads();

    const int w = tid >> 6;           // wave id; rows w*32 .. w*32+31
#pragma unroll 2
    for (int j = 0; j < 16; ++j) {
        const int r = w * 32 + 2 * j + hi;              // 2 rows per iter
        const float4* hr = &hs4[r * 16];                // 2 unique addrs/instr
        float a0 = bias, a1 = 0.0f, a2 = 0.0f, a3 = 0.0f;
#pragma unroll
        for (int k = 0; k < 16; ++k) {
            const float4 hb = hr[k];
            a0 = fmaf(wfc[4 * k + 0], hb.x, a0);
            a1 = fmaf(wfc[4 * k + 1], hb.y, a1);
            a2 = fmaf(wfc[4 * k + 2], hb.z, a2);
            a3 = fmaf(wfc[4 * k + 3], hb.w, a3);
        }
        obs[(row0 + r) * O_DIM + o] = (a0 + a1) + (a2 + a3);  // coalesced
    }
}

extern "C" void kernel_launch(void* const* d_in, const int* in_sizes, int n_in,
                              void* d_out, int out_size, void* d_ws, size_t ws_size,
                              hipStream_t stream)
{
    const float* x   = (const float*)d_in[0];
    const float* Wih = (const float*)d_in[1];
    const float* bih = (const float*)d_in[2];
    const float* Whh = (const float*)d_in[3];
    const float* bhh = (const float*)d_in[4];
    const float* Wfc = (const float*)d_in[5];
    const float* bfc = (const float*)d_in[6];

    float* out    = (float*)d_out;
    float* obs    = out;                         // [8,32,2048,32]
    float* hidden = out + (size_t)OBS_ELEMS;     // [8,32,2048,64]
    float* hlast  = hidden + (size_t)HID_ELEMS;  // [8,32,64]

    // pre is materialized IN the hidden buffer (same shape), then the scan
    // overwrites it in place (reads run 8 steps ahead of writes).
    pre_kernel<<<NROWS / 128, 256, 0, stream>>>(x, Wih, bih, bhh, hidden);
    rnn_scan_kernel<<<NSEQ, 64, 0, stream>>>(Whh, hidden, hlast);
    obs_kernel<<<NROWS / 128, 256, 0, stream>>>(hidden, Wfc, bfc, obs);
}